// Round 14
// baseline (275.816 us; speedup 1.0000x reference)
//
#include <hip/hip_runtime.h>
#include <hip/hip_bf16.h>
#include <math.h>

#define GENES 1000

typedef __attribute__((ext_vector_type(8))) _Float16 half8;
typedef __attribute__((ext_vector_type(4))) float f32x4;
typedef __attribute__((ext_vector_type(4))) unsigned int uint4v;
typedef __attribute__((ext_vector_type(2))) unsigned int uint2v;

__device__ inline float f16lo(unsigned int v) {
  return (float)__builtin_bit_cast(_Float16, (unsigned short)(v & 0xffffu));
}
__device__ inline float f16hi(unsigned int v) {
  return (float)__builtin_bit_cast(_Float16, (unsigned short)(v >> 16));
}

// ---------------- CSR build ----------------

__global__ void k_deg(const int* __restrict__ ei, int* __restrict__ deg, int E) {
  int e = blockIdx.x * blockDim.x + threadIdx.x;
  if (e < E) atomicAdd(&deg[ei[E + e]], 1);
}

// reads deg, zeroes it in place (replaces the second memset before k_scatter)
__global__ void k_scan1(int* __restrict__ deg, int* __restrict__ ptr,
                        int* __restrict__ bsum, int n) {
  __shared__ int ws[4];
  int t = threadIdx.x, b = blockIdx.x;
  int i = b * 256 + t;
  int lane = t & 63, w = t >> 6;
  int x = 0;
  if (i < n) { x = deg[i]; deg[i] = 0; }
  #pragma unroll
  for (int d = 1; d < 64; d <<= 1) {
    int y = __shfl_up(x, d);
    if (lane >= d) x += y;
  }
  if (lane == 63) ws[w] = x;
  __syncthreads();
  if (t == 0) {
    int s = 0;
    #pragma unroll
    for (int k = 0; k < 4; ++k) { s += ws[k]; ws[k] = s; }
  }
  __syncthreads();
  int incl = x + (w ? ws[w - 1] : 0);
  if (i < n) ptr[i + 1] = incl;
  if (t == 255) bsum[b] = incl;
  if (i == 0) ptr[0] = 0;
}

__global__ void k_scan2(int* __restrict__ bsum, int nb) {
  __shared__ int ws[4];
  int t = threadIdx.x;
  int lane = t & 63, w = t >> 6;
  int v = (t < nb) ? bsum[t] : 0;
  int x = v;
  #pragma unroll
  for (int d = 1; d < 64; d <<= 1) {
    int y = __shfl_up(x, d);
    if (lane >= d) x += y;
  }
  if (lane == 63) ws[w] = x;
  __syncthreads();
  if (t == 0) {
    int s = 0;
    #pragma unroll
    for (int k = 0; k < 4; ++k) { s += ws[k]; ws[k] = s; }
  }
  __syncthreads();
  int incl = x + (w ? ws[w - 1] : 0);
  if (t < nb) bsum[t] = incl - v;
}

__global__ void k_scan3(int* __restrict__ ptr, const int* __restrict__ bsum, int n) {
  int i = blockIdx.x * 256 + threadIdx.x;
  if (i < n) ptr[i + 1] += bsum[blockIdx.x];
}

__global__ void k_scatter(const int* __restrict__ ei, const int* __restrict__ ptr,
                          int* __restrict__ cur, int* __restrict__ srcs, int E) {
  int e = blockIdx.x * blockDim.x + threadIdx.x;
  if (e >= E) return;
  int d = ei[E + e];
  int pos = ptr[d] + atomicAdd(&cur[d], 1);
  srcs[pos] = ei[e];
}

// ---------------- W pack (all 3 layers, one launch), q-major per k-step --------

__global__ void k_wpackall(const float* __restrict__ W0, const float* __restrict__ W1,
                           const float* __restrict__ W2, unsigned short* __restrict__ P,
                           int K0) {
  int t = blockIdx.x * blockDim.x + threadIdx.x;  // 163840 total
  if (t >= 163840) return;
  const float* W; int K, N, e;
  if (t < 131072)      { W = W0; K = K0;  N = 128; e = t; }
  else if (t < 147456) { W = W1; K = 128; N = 128; e = t - 131072; }
  else                 { W = W2; K = 128; N = 16;  e = t - 147456; }
  int s = e >> 12, rem = e & 4095;
  int q = rem >> 10, col = (rem >> 3) & 127, j = rem & 7;
  int k = s * 32 + q * 8 + j;
  float v = (k < K && col < N) ? W[(long)k * N + col] : 0.f;
  _Float16 h = (_Float16)v;
  P[t] = __builtin_bit_cast(unsigned short, h);
}

// ---------------- MFMA fp16 GEMM, 64-VGPR budget, depth-2 A pipeline -----------
// 512 threads = 8 waves (4 row-groups x 2 col-groups); BM=64, BN=128, BK=32.
// 3 named A-register slots (tile%3, static under full unroll) push the A
// global_load -> ds_write distance to 2 half-steps (~2x latency cover) while
// staying within the 64-VGPR budget (acc16 + A12 + B16 + addr ~= 56).
// LDS: A dbuf 2x4KB (q-major fp16) + B dbuf 2x8KB (q-major) = 24KB.
// Fused epilogue: out (fp16/fp32) + attention coefficients als/ald.

template<int HH, int NST, bool AF16, bool OF16>
__global__ __launch_bounds__(512) void k_mgemm8(
    const void* __restrict__ Ap, const unsigned short* __restrict__ Pb,
    void* __restrict__ outp, float* __restrict__ als, float* __restrict__ ald,
    const float* __restrict__ avs, const float* __restrict__ avd,
    int M, int K, int ldc) {
  __shared__ __align__(16) char lds[24576];
  char* bA0 = lds;
  char* bA1 = lds + 4096;
  char* bB0 = lds + 8192;
  char* bB1 = lds + 16384;

  int t = threadIdx.x, lane = t & 63;
  int r15 = lane & 15, q = lane >> 4;
  int wv = t >> 6;
  int wr = wv >> 1, wc = wv & 1;
  long row0 = (long)blockIdx.x * 64;

  int srow = t >> 3, sseg = t & 7;
  long arow = row0 + srow; if (arow >= M) arow = M - 1;
  const float* pa32 = (const float*)Ap + arow * (long)K;
  const unsigned short* pa16 = (const unsigned short*)Ap + arow * (long)K;

  f32x4 acc[4];
  #pragma unroll
  for (int nt = 0; nt < 4; ++nt) acc[nt] = (f32x4){0.f, 0.f, 0.f, 0.f};

  // 3 A slots, 2 B slots (named registers; slot index always constant-folded)
  uint4v aA0, aA1, aA2;
  uint2v aH0, aH1, aH2;
  uint4v rB0, rB1;

  auto loadA = [&](int s, uint4v& r32, uint2v& r16) {
    int k0 = s * 32 + sseg * 4;
    if constexpr (AF16) {
      r16 = (k0 < K) ? *(const uint2v*)(pa16 + k0) : (uint2v){0u, 0u};
    } else {
      r32 = (k0 < K) ? *(const uint4v*)(pa32 + k0) : (uint4v){0u, 0u, 0u, 0u};
    }
  };
  auto writeA = [&](char* buf, uint4v r32, uint2v r16) {
    char* p = buf + ((sseg >> 1) * 1024 + srow * 16 + (sseg & 1) * 8);
    if constexpr (AF16) {
      *(uint2v*)p = r16;
    } else {
      float4 f = __builtin_bit_cast(float4, r32);
      uint2v h;
      h[0] = __builtin_bit_cast(unsigned int, __builtin_amdgcn_cvt_pkrtz(f.x, f.y));
      h[1] = __builtin_bit_cast(unsigned int, __builtin_amdgcn_cvt_pkrtz(f.z, f.w));
      *(uint2v*)p = h;
    }
  };
  auto ldA3 = [&](int tile) {
    int sl = tile % 3;
    if (sl == 0) loadA(tile, aA0, aH0);
    else if (sl == 1) loadA(tile, aA1, aH1);
    else loadA(tile, aA2, aH2);
  };
  auto wrA3 = [&](char* buf, int tile) {
    int sl = tile % 3;
    if (sl == 0) writeA(buf, aA0, aH0);
    else if (sl == 1) writeA(buf, aA1, aH1);
    else writeA(buf, aA2, aH2);
  };
  auto loadB = [&](int s, uint4v& r) {
    r = *(const uint4v*)(Pb + (size_t)s * 4096 + t * 8);
  };
  auto writeB = [&](char* buf, uint4v r) {
    *(uint4v*)(buf + t * 16) = r;
  };
  auto compute = [&](const char* bA, const char* bB) {
    half8 af = *(const half8*)(bA + q * 1024 + (wr * 16 + r15) * 16);
    #pragma unroll
    for (int nt = 0; nt < 4; ++nt) {
      half8 bf = *(const half8*)(bB + q * 2048 + (wc * 64 + nt * 16 + r15) * 16);
      acc[nt] = __builtin_amdgcn_mfma_f32_16x16x32_f16(af, bf, acc[nt], 0, 0, 0);
    }
  };

  // prologue: tiles 0,1,2 in flight; tile 0 staged (NST >= 4 everywhere)
  ldA3(0); loadB(0, rB0);
  ldA3(1); loadB(1, rB1);
  ldA3(2);
  wrA3(bA0, 0); writeB(bB0, rB0);
  __syncthreads();

  #pragma unroll
  for (int s = 0; s < NST; s += 2) {
    // half-step X: compute tile s (buf0)
    if (s + 3 < NST) ldA3(s + 3);
    if (s + 2 < NST) loadB(s + 2, rB0);
    compute(bA0, bB0);
    if (s + 1 < NST) { wrA3(bA1, s + 1); writeB(bB1, rB1); }
    __syncthreads();
    // half-step Y: compute tile s+1 (buf1)
    if (s + 1 < NST) {
      if (s + 4 < NST) ldA3(s + 4);
      if (s + 3 < NST) loadB(s + 3, rB1);
      compute(bA1, bB1);
      if (s + 2 < NST) { wrA3(bA0, s + 2); writeB(bB0, rB0); }
      __syncthreads();
    }
  }

  long rbase = row0 + wr * 16 + q * 4;
  if constexpr (OF16) {
    unsigned short* o16 = (unsigned short*)outp;
    #pragma unroll
    for (int i = 0; i < 4; ++i) {
      long r = rbase + i;
      if (r < M) {
        #pragma unroll
        for (int nt = 0; nt < 4; ++nt) {
          int col = wc * 64 + nt * 16 + r15;
          _Float16 hv = (_Float16)acc[nt][i];
          o16[r * ldc + col] = __builtin_bit_cast(unsigned short, hv);
        }
      }
    }
  } else {
    float* o32 = (float*)outp;
    #pragma unroll
    for (int i = 0; i < 4; ++i) {
      long r = rbase + i;
      if (r < M) {
        #pragma unroll
        for (int nt = 0; nt < 4; ++nt) {
          int col = wc * 64 + nt * 16 + r15;
          if (col < ldc) o32[r * ldc + col] = acc[nt][i];
        }
      }
    }
  }
  #pragma unroll
  for (int nt = 0; nt < 4; ++nt) {
    int head = wc * 4 + nt;
    if (head < HH) {
      float cs = avs[head * 16 + r15];
      float cd = avd[head * 16 + r15];
      #pragma unroll
      for (int i = 0; i < 4; ++i) {
        float s1 = acc[nt][i] * cs;
        float s2 = acc[nt][i] * cd;
        #pragma unroll
        for (int d = 1; d < 16; d <<= 1) {
          s1 += __shfl_xor(s1, d);
          s2 += __shfl_xor(s2, d);
        }
        if (r15 == 0) {
          long r = rbase + i;
          if (r < M) { als[r * HH + head] = s1; ald[r * HH + head] = s2; }
        }
      }
    }
  }
}

// ---------------- per-dst aggregation, H=8, C=16, fp16 h, ELU ------------------
// Split-wave: two independent 32-lane halves, alternate edges, 4-edge batches;
// cross-half merge via shfl_xor(32). No max pass (shift-invariant softmax).

__global__ void k_agg128h(const unsigned short* __restrict__ h,
                          const float* __restrict__ als, const float* __restrict__ ald,
                          const int* __restrict__ ptr, const int* __restrict__ srcs,
                          const float* __restrict__ bias,
                          unsigned short* __restrict__ out, int n) {
  int wid = (int)(((long)blockIdx.x * blockDim.x + threadIdx.x) >> 6);
  if (wid >= n) return;
  int lane = threadIdx.x & 63;
  int half = lane >> 5, l5 = lane & 31;
  int c0 = 4 * l5;
  int hB = l5 >> 2;
  int p0 = ptr[wid], deg = ptr[wid + 1] - p0;
  float aldB = ald[wid * 8 + hB];
  float a0 = 0.f, a1 = 0.f, a2 = 0.f, a3 = 0.f, dsum = 0.f;
  int j = half;
  for (; j + 6 < deg; j += 8) {
    int s0 = srcs[p0 + j],     s1 = srcs[p0 + j + 2];
    int s2 = srcs[p0 + j + 4], s3 = srcs[p0 + j + 6];
    float l0 = als[s0 * 8 + hB] + aldB;
    float l1 = als[s1 * 8 + hB] + aldB;
    float l2 = als[s2 * 8 + hB] + aldB;
    float l3 = als[s3 * 8 + hB] + aldB;
    uint2v h0 = *(const uint2v*)(h + (long)s0 * 128 + c0);
    uint2v h1 = *(const uint2v*)(h + (long)s1 * 128 + c0);
    uint2v h2 = *(const uint2v*)(h + (long)s2 * 128 + c0);
    uint2v h3 = *(const uint2v*)(h + (long)s3 * 128 + c0);
    l0 = l0 > 0.f ? l0 : 0.2f * l0;
    l1 = l1 > 0.f ? l1 : 0.2f * l1;
    l2 = l2 > 0.f ? l2 : 0.2f * l2;
    l3 = l3 > 0.f ? l3 : 0.2f * l3;
    float e0 = __expf(l0), e1 = __expf(l1), e2 = __expf(l2), e3 = __expf(l3);
    dsum += e0 + e1 + e2 + e3;
    a0 += e0 * f16lo(h0[0]) + e1 * f16lo(h1[0]) + e2 * f16lo(h2[0]) + e3 * f16lo(h3[0]);
    a1 += e0 * f16hi(h0[0]) + e1 * f16hi(h1[0]) + e2 * f16hi(h2[0]) + e3 * f16hi(h3[0]);
    a2 += e0 * f16lo(h0[1]) + e1 * f16lo(h1[1]) + e2 * f16lo(h2[1]) + e3 * f16lo(h3[1]);
    a3 += e0 * f16hi(h0[1]) + e1 * f16hi(h1[1]) + e2 * f16hi(h2[1]) + e3 * f16hi(h3[1]);
  }
  for (; j < deg; j += 2) {
    int s = srcs[p0 + j];
    float l = als[s * 8 + hB] + aldB;
    l = l > 0.f ? l : 0.2f * l;
    float e = __expf(l);
    uint2v hv = *(const uint2v*)(h + (long)s * 128 + c0);
    dsum += e;
    a0 += e * f16lo(hv[0]);
    a1 += e * f16hi(hv[0]);
    a2 += e * f16lo(hv[1]);
    a3 += e * f16hi(hv[1]);
  }
  a0 += __shfl_xor(a0, 32);
  a1 += __shfl_xor(a1, 32);
  a2 += __shfl_xor(a2, 32);
  a3 += __shfl_xor(a3, 32);
  dsum += __shfl_xor(dsum, 32);
  if (half == 0) {
    float inv = 1.f / (dsum + 1e-16f);
    float o0 = a0 * inv + bias[c0];
    float o1 = a1 * inv + bias[c0 + 1];
    float o2 = a2 * inv + bias[c0 + 2];
    float o3 = a3 * inv + bias[c0 + 3];
    o0 = o0 > 0.f ? o0 : (__expf(o0) - 1.f);
    o1 = o1 > 0.f ? o1 : (__expf(o1) - 1.f);
    o2 = o2 > 0.f ? o2 : (__expf(o2) - 1.f);
    o3 = o3 > 0.f ? o3 : (__expf(o3) - 1.f);
    uint2v po;
    po[0] = __builtin_bit_cast(unsigned int, __builtin_amdgcn_cvt_pkrtz(o0, o1));
    po[1] = __builtin_bit_cast(unsigned int, __builtin_amdgcn_cvt_pkrtz(o2, o3));
    *(uint2v*)(out + (long)wid * 128 + c0) = po;
  }
}

// ---------------- per-dst aggregation, H=1, C=16, fp32, no max, 4-batch --------

__global__ void k_agg16(const float* __restrict__ h, const float* __restrict__ als,
                        const float* __restrict__ ald, const int* __restrict__ ptr,
                        const int* __restrict__ srcs, const float* __restrict__ bias,
                        float* __restrict__ out, int n, int lda) {
  int wid = (int)(((long)blockIdx.x * blockDim.x + threadIdx.x) >> 6);
  if (wid >= n) return;
  int lane = threadIdx.x & 63;
  int p0 = ptr[wid], deg = ptr[wid + 1] - p0;
  float aldv = ald[wid];
  int g = lane >> 4, c = lane & 15;
  float acc = 0.f, dsum = 0.f;
  int j = g;
  for (; j + 12 < deg; j += 16) {
    int s0 = srcs[p0 + j],     s1 = srcs[p0 + j + 4];
    int s2 = srcs[p0 + j + 8], s3 = srcs[p0 + j + 12];
    float l0 = als[s0] + aldv, l1 = als[s1] + aldv;
    float l2 = als[s2] + aldv, l3 = als[s3] + aldv;
    float h0 = h[(long)s0 * lda + c], h1 = h[(long)s1 * lda + c];
    float h2 = h[(long)s2 * lda + c], h3 = h[(long)s3 * lda + c];
    l0 = l0 > 0.f ? l0 : 0.2f * l0;
    l1 = l1 > 0.f ? l1 : 0.2f * l1;
    l2 = l2 > 0.f ? l2 : 0.2f * l2;
    l3 = l3 > 0.f ? l3 : 0.2f * l3;
    float e0 = __expf(l0), e1 = __expf(l1), e2 = __expf(l2), e3 = __expf(l3);
    dsum += e0 + e1 + e2 + e3;
    acc += e0 * h0 + e1 * h1 + e2 * h2 + e3 * h3;
  }
  for (; j < deg; j += 4) {
    int s = srcs[p0 + j];
    float l = als[s] + aldv;
    l = l > 0.f ? l : 0.2f * l;
    float e = __expf(l);
    dsum += e;
    acc += e * h[(long)s * lda + c];
  }
  #pragma unroll
  for (int d = 16; d < 64; d <<= 1) {
    acc += __shfl_xor(acc, d);
    dsum += __shfl_xor(dsum, d);
  }
  if (lane < 16)
    out[(long)wid * 16 + lane] = acc / (dsum + 1e-16f) + bias[lane];
}

// ---------------- launch ----------------

extern "C" void kernel_launch(void* const* d_in, const int* in_sizes, int n_in,
                              void* d_out, int out_size, void* d_ws, size_t ws_size,
                              hipStream_t stream) {
  const float* x  = (const float*)d_in[0];
  const int*   ei = (const int*)d_in[1];
  const float* W0 = (const float*)d_in[2];
  const float* as0= (const float*)d_in[3];
  const float* ad0= (const float*)d_in[4];
  const float* b0 = (const float*)d_in[5];
  const float* W1 = (const float*)d_in[6];
  const float* as1= (const float*)d_in[7];
  const float* ad1= (const float*)d_in[8];
  const float* b1 = (const float*)d_in[9];
  const float* W2 = (const float*)d_in[10];
  const float* as2= (const float*)d_in[11];
  const float* ad2= (const float*)d_in[12];
  const float* b2 = (const float*)d_in[13];
  float* out = (float*)d_out;

  int E = in_sizes[1] / 2;
  int n = in_sizes[0] / GENES;

  char* ws = (char*)d_ws;
  size_t off = 0;
  auto alloc = [&](size_t bytes) {
    void* p = ws + off;
    off = (off + bytes + 255) & ~(size_t)255;
    return p;
  };
  int* ptr   = (int*)alloc((size_t)(n + 1) * sizeof(int));
  int* cur   = (int*)alloc((size_t)n * sizeof(int));
  int* bsum  = (int*)alloc(512 * sizeof(int));
  int* srcs  = (int*)alloc((size_t)E * sizeof(int));
  unsigned short* Ah = (unsigned short*)alloc((size_t)n * 128 * sizeof(unsigned short));
  unsigned short* Bh = (unsigned short*)alloc((size_t)n * 128 * sizeof(unsigned short));
  float* A2  = (float*)alloc((size_t)n * 16 * sizeof(float));
  float* als = (float*)alloc((size_t)n * 8 * sizeof(float));
  float* ald = (float*)alloc((size_t)n * 8 * sizeof(float));
  unsigned short* P = (unsigned short*)alloc((size_t)163840 * sizeof(unsigned short));
  unsigned short* P0 = P;
  unsigned short* P1 = P + 131072;
  unsigned short* P2 = P + 147456;

  int eb = (E + 255) / 256;
  int nb = (n + 255) / 256;
  hipMemsetAsync(cur, 0, (size_t)n * sizeof(int), stream);
  k_deg<<<eb, 256, 0, stream>>>(ei, cur, E);
  k_scan1<<<nb, 256, 0, stream>>>(cur, ptr, bsum, n);   // zeroes cur in place
  k_scan2<<<1, 256, 0, stream>>>(bsum, nb);
  k_scan3<<<nb, 256, 0, stream>>>(ptr, bsum, n);
  k_scatter<<<eb, 256, 0, stream>>>(ei, ptr, cur, srcs, E);
  k_wpackall<<<640, 256, 0, stream>>>(W0, W1, W2, P, GENES);

  int mgb  = (n + 63) / 64;
  int aggb = (int)(((long)n * 64 + 255) / 256);

  // layer 0: x @ W0 -> Ah fp16 (+als/ald), aggregate -> Bh fp16 (ELU)
  k_mgemm8<8, 32, false, true><<<mgb, 512, 0, stream>>>(
      x, P0, Ah, als, ald, as0, ad0, n, GENES, 128);
  k_agg128h<<<aggb, 256, 0, stream>>>(Ah, als, ald, ptr, srcs, b0, Bh, n);

  // layer 1: Bh @ W1 -> Ah fp16 (+als/ald), aggregate -> Bh fp16 (ELU)
  k_mgemm8<8, 4, true, true><<<mgb, 512, 0, stream>>>(
      Bh, P1, Ah, als, ald, as1, ad1, n, 128, 128);
  k_agg128h<<<aggb, 256, 0, stream>>>(Ah, als, ald, ptr, srcs, b1, Bh, n);

  // layer 2: Bh @ W2 (padded) -> A2 fp32 [n][16] (+als/ald H=1), aggregate -> out
  k_mgemm8<1, 4, true, false><<<mgb, 512, 0, stream>>>(
      Bh, P2, A2, als, ald, as2, ad2, n, 128, 16);
  k_agg16<<<aggb, 256, 0, stream>>>(A2, als, ald, ptr, srcs, b2, out, n, 16);
}

// Round 15
// 274.300 us; speedup vs baseline: 1.0055x; 1.0055x over previous
//
#include <hip/hip_runtime.h>
#include <hip/hip_bf16.h>
#include <math.h>

#define GENES 1000

typedef __attribute__((ext_vector_type(8))) _Float16 half8;
typedef __attribute__((ext_vector_type(4))) float f32x4;
typedef __attribute__((ext_vector_type(4))) unsigned int uint4v;
typedef __attribute__((ext_vector_type(2))) unsigned int uint2v;

__device__ inline float f16lo(unsigned int v) {
  return (float)__builtin_bit_cast(_Float16, (unsigned short)(v & 0xffffu));
}
__device__ inline float f16hi(unsigned int v) {
  return (float)__builtin_bit_cast(_Float16, (unsigned short)(v >> 16));
}
__device__ inline unsigned int pk(float a, float b) {
  return __builtin_bit_cast(unsigned int, __builtin_amdgcn_cvt_pkrtz(a, b));
}

// ---------------- CSR build ----------------

__global__ void k_deg(const int* __restrict__ ei, int* __restrict__ deg, int E) {
  int e = blockIdx.x * blockDim.x + threadIdx.x;
  if (e < E) atomicAdd(&deg[ei[E + e]], 1);
}

__global__ void k_scan1(int* __restrict__ deg, int* __restrict__ ptr,
                        int* __restrict__ bsum, int n) {
  __shared__ int ws[4];
  int t = threadIdx.x, b = blockIdx.x;
  int i = b * 256 + t;
  int lane = t & 63, w = t >> 6;
  int x = 0;
  if (i < n) { x = deg[i]; deg[i] = 0; }
  #pragma unroll
  for (int d = 1; d < 64; d <<= 1) {
    int y = __shfl_up(x, d);
    if (lane >= d) x += y;
  }
  if (lane == 63) ws[w] = x;
  __syncthreads();
  if (t == 0) {
    int s = 0;
    #pragma unroll
    for (int k = 0; k < 4; ++k) { s += ws[k]; ws[k] = s; }
  }
  __syncthreads();
  int incl = x + (w ? ws[w - 1] : 0);
  if (i < n) ptr[i + 1] = incl;
  if (t == 255) bsum[b] = incl;
  if (i == 0) ptr[0] = 0;
}

__global__ void k_scan2(int* __restrict__ bsum, int nb) {
  __shared__ int ws[4];
  int t = threadIdx.x;
  int lane = t & 63, w = t >> 6;
  int v = (t < nb) ? bsum[t] : 0;
  int x = v;
  #pragma unroll
  for (int d = 1; d < 64; d <<= 1) {
    int y = __shfl_up(x, d);
    if (lane >= d) x += y;
  }
  if (lane == 63) ws[w] = x;
  __syncthreads();
  if (t == 0) {
    int s = 0;
    #pragma unroll
    for (int k = 0; k < 4; ++k) { s += ws[k]; ws[k] = s; }
  }
  __syncthreads();
  int incl = x + (w ? ws[w - 1] : 0);
  if (t < nb) bsum[t] = incl - v;
}

__global__ void k_scan3(int* __restrict__ ptr, const int* __restrict__ bsum, int n) {
  int i = blockIdx.x * 256 + threadIdx.x;
  if (i < n) ptr[i + 1] += bsum[blockIdx.x];
}

__global__ void k_scatter(const int* __restrict__ ei, const int* __restrict__ ptr,
                          int* __restrict__ cur, int* __restrict__ srcs, int E) {
  int e = blockIdx.x * blockDim.x + threadIdx.x;
  if (e >= E) return;
  int d = ei[E + e];
  int pos = ptr[d] + atomicAdd(&cur[d], 1);
  srcs[pos] = ei[e];
}

// ---------------- W pack: per 128-k macro chunk, [ks][q][col][8] fp16 ----------
// element e in region: c = e>>14, ks=(e>>12)&3, q=(e>>10)&3, col=(e>>3)&127,
// j=e&7; k = c*128 + ks*32 + q*8 + j.
// W0 -> 8 macros (K padded 1024), W1 -> 1, W2 -> 1 (cols padded to 128).

__global__ void k_wpackall(const float* __restrict__ W0, const float* __restrict__ W1,
                           const float* __restrict__ W2, unsigned short* __restrict__ P,
                           int K0) {
  int t = blockIdx.x * blockDim.x + threadIdx.x;  // 163840 total
  if (t >= 163840) return;
  const float* W; int K, N, e;
  if (t < 131072)      { W = W0; K = K0;  N = 128; e = t; }
  else if (t < 147456) { W = W1; K = 128; N = 128; e = t - 131072; }
  else                 { W = W2; K = 128; N = 16;  e = t - 147456; }
  int c = e >> 14, ks = (e >> 12) & 3, q = (e >> 10) & 3;
  int col = (e >> 3) & 127, j = e & 7;
  int k = c * 128 + ks * 32 + q * 8 + j;
  float v = (k < K && col < N) ? W[(long)k * N + col] : 0.f;
  _Float16 h = (_Float16)v;
  P[t] = __builtin_bit_cast(unsigned short, h);
}

// ---------------- MFMA fp16 GEMM, BK=128 macro-steps --------------------------
// 512 threads = 8 waves (4 row-groups x 2 col-groups); BM=64, BN=128.
// Per macro: block reads 64 rows x 512B CONTIGUOUS of A (4x the DRAM quantum of
// BK=32) and 32KB of packed B; 2 barriers per macro (16 total at K=1024).
// A+B single-buffered LDS = 48.3KB -> 3 blocks/CU, 24 waves/CU. Loads for macro
// c+1 issue after barrier (b) -> drained at next macro's barrier (a): cover =
// full 16-MFMA compute phase. Named staging regs (no arrays): acc16+A16+B16.
// A LDS q-stride 1040 (pad) -> staging writes 2-way aliased (free), fragment
// reads 256B-contiguous. Fused epilogue: out + als/ald.

template<int HH, bool AF16, bool OF16>
__global__ __launch_bounds__(512) void k_mgemm9(
    const void* __restrict__ Ap, const unsigned short* __restrict__ Pb,
    void* __restrict__ outp, float* __restrict__ als, float* __restrict__ ald,
    const float* __restrict__ avs, const float* __restrict__ avd,
    int M, int K, int nmac, int ldc) {
  __shared__ __align__(16) char lds[16640 + 32768];
  char* As = lds;            // [4 ks][4 q (stride 1040)][64 row][16B]
  char* Bs = lds + 16640;    // [4 ks][4 q][128 col][16B] linear

  int t = threadIdx.x, lane = t & 63;
  int r15 = lane & 15, q = lane >> 4;
  int wv = t >> 6;
  int wr = wv >> 1, wc = wv & 1;
  long row0 = (long)blockIdx.x * 64;

  // A staging: thread -> row (t>>3), 16-float segment seg (t&7)
  int srow = t >> 3, seg = t & 7;
  long arow = row0 + srow; if (arow >= M) arow = M - 1;
  const float* pa32 = (const float*)Ap + arow * (long)K;
  const unsigned short* pa16 = (const unsigned short*)Ap + arow * (long)K;
  int aks = seg >> 1, aq0 = (seg & 1) * 2;
  char* wA0 = As + aks * 4160 + aq0 * 1040 + srow * 16;
  char* wA1 = wA0 + 1040;
  const char* pbB = (const char*)Pb;

  f32x4 acc[4];
  #pragma unroll
  for (int nt = 0; nt < 4; ++nt) acc[nt] = (f32x4){0.f, 0.f, 0.f, 0.f};

  // named staging registers (single set, reused per macro)
  uint4v a0, a1, a2, a3;   // fp32 path: 16 floats; fp16 path: a0,a1 = 16 halves
  uint4v b0, b1, b2, b3;

  auto issueA = [&](int c) {
    int k0 = c * 128 + seg * 16;
    if constexpr (AF16) {
      uint4v z = (uint4v){0u,0u,0u,0u};
      a0 = (k0 + 8 <= K)  ? *(const uint4v*)(pa16 + k0)     : z;
      a1 = (k0 + 16 <= K) ? *(const uint4v*)(pa16 + k0 + 8) : z;
    } else {
      if (k0 + 16 <= K) {
        a0 = *(const uint4v*)(pa32 + k0);
        a1 = *(const uint4v*)(pa32 + k0 + 4);
        a2 = *(const uint4v*)(pa32 + k0 + 8);
        a3 = *(const uint4v*)(pa32 + k0 + 12);
      } else {
        float tmp[16];
        #pragma unroll
        for (int ii = 0; ii < 16; ++ii)
          tmp[ii] = (k0 + ii < K) ? pa32[k0 + ii] : 0.f;
        a0 = __builtin_bit_cast(uint4v, make_float4(tmp[0], tmp[1], tmp[2], tmp[3]));
        a1 = __builtin_bit_cast(uint4v, make_float4(tmp[4], tmp[5], tmp[6], tmp[7]));
        a2 = __builtin_bit_cast(uint4v, make_float4(tmp[8], tmp[9], tmp[10], tmp[11]));
        a3 = __builtin_bit_cast(uint4v, make_float4(tmp[12], tmp[13], tmp[14], tmp[15]));
      }
    }
  };
  auto issueB = [&](int c) {
    const char* p = pbB + (size_t)c * 32768 + t * 16;
    b0 = *(const uint4v*)(p);
    b1 = *(const uint4v*)(p + 8192);
    b2 = *(const uint4v*)(p + 16384);
    b3 = *(const uint4v*)(p + 24576);
  };
  auto writeA = [&]() {
    if constexpr (AF16) {
      *(uint4v*)wA0 = a0;
      *(uint4v*)wA1 = a1;
    } else {
      float4 f0 = __builtin_bit_cast(float4, a0);
      float4 f1 = __builtin_bit_cast(float4, a1);
      float4 f2 = __builtin_bit_cast(float4, a2);
      float4 f3 = __builtin_bit_cast(float4, a3);
      uint4v h0, h1;
      h0[0] = pk(f0.x, f0.y); h0[1] = pk(f0.z, f0.w);
      h0[2] = pk(f1.x, f1.y); h0[3] = pk(f1.z, f1.w);
      h1[0] = pk(f2.x, f2.y); h1[1] = pk(f2.z, f2.w);
      h1[2] = pk(f3.x, f3.y); h1[3] = pk(f3.z, f3.w);
      *(uint4v*)wA0 = h0;
      *(uint4v*)wA1 = h1;
    }
  };
  auto writeB = [&]() {
    char* p = Bs + t * 16;
    *(uint4v*)(p)         = b0;
    *(uint4v*)(p + 8192)  = b1;
    *(uint4v*)(p + 16384) = b2;
    *(uint4v*)(p + 24576) = b3;
  };

  issueA(0); issueB(0);

  for (int c = 0; c < nmac; ++c) {
    __syncthreads();          // (a) LDS free; drains loads issued last compute
    writeA();
    writeB();
    __syncthreads();          // (b) staging visible; no vm loads pending
    if (c + 1 < nmac) { issueA(c + 1); issueB(c + 1); }
    #pragma unroll
    for (int ks2 = 0; ks2 < 4; ++ks2) {
      half8 af = *(const half8*)(As + ks2 * 4160 + q * 1040 + (wr * 16 + r15) * 16);
      #pragma unroll
      for (int nt = 0; nt < 4; ++nt) {
        half8 bf = *(const half8*)(Bs + ks2 * 8192 + q * 2048 +
                                   (wc * 64 + nt * 16 + r15) * 16);
        acc[nt] = __builtin_amdgcn_mfma_f32_16x16x32_f16(af, bf, acc[nt], 0, 0, 0);
      }
    }
  }

  // ---- epilogue: C/D layout col=lane&15, row=(lane>>4)*4+i ----
  long rbase = row0 + wr * 16 + q * 4;
  if constexpr (OF16) {
    unsigned short* o16 = (unsigned short*)outp;
    #pragma unroll
    for (int i = 0; i < 4; ++i) {
      long r = rbase + i;
      if (r < M) {
        #pragma unroll
        for (int nt = 0; nt < 4; ++nt) {
          int col = wc * 64 + nt * 16 + r15;
          _Float16 hv = (_Float16)acc[nt][i];
          o16[r * ldc + col] = __builtin_bit_cast(unsigned short, hv);
        }
      }
    }
  } else {
    float* o32 = (float*)outp;
    #pragma unroll
    for (int i = 0; i < 4; ++i) {
      long r = rbase + i;
      if (r < M) {
        #pragma unroll
        for (int nt = 0; nt < 4; ++nt) {
          int col = wc * 64 + nt * 16 + r15;
          if (col < ldc) o32[r * ldc + col] = acc[nt][i];
        }
      }
    }
  }
  #pragma unroll
  for (int nt = 0; nt < 4; ++nt) {
    int head = wc * 4 + nt;
    if (head < HH) {
      float cs = avs[head * 16 + r15];
      float cd = avd[head * 16 + r15];
      #pragma unroll
      for (int i = 0; i < 4; ++i) {
        float s1 = acc[nt][i] * cs;
        float s2 = acc[nt][i] * cd;
        #pragma unroll
        for (int d = 1; d < 16; d <<= 1) {
          s1 += __shfl_xor(s1, d);
          s2 += __shfl_xor(s2, d);
        }
        if (r15 == 0) {
          long r = rbase + i;
          if (r < M) { als[r * HH + head] = s1; ald[r * HH + head] = s2; }
        }
      }
    }
  }
}

// ---------------- per-dst aggregation, H=8, C=16, fp16 h, ELU ------------------

__global__ void k_agg128h(const unsigned short* __restrict__ h,
                          const float* __restrict__ als, const float* __restrict__ ald,
                          const int* __restrict__ ptr, const int* __restrict__ srcs,
                          const float* __restrict__ bias,
                          unsigned short* __restrict__ out, int n) {
  int wid = (int)(((long)blockIdx.x * blockDim.x + threadIdx.x) >> 6);
  if (wid >= n) return;
  int lane = threadIdx.x & 63;
  int half = lane >> 5, l5 = lane & 31;
  int c0 = 4 * l5;
  int hB = l5 >> 2;
  int p0 = ptr[wid], deg = ptr[wid + 1] - p0;
  float aldB = ald[wid * 8 + hB];
  float a0 = 0.f, a1 = 0.f, a2 = 0.f, a3 = 0.f, dsum = 0.f;
  int j = half;
  for (; j + 6 < deg; j += 8) {
    int s0 = srcs[p0 + j],     s1 = srcs[p0 + j + 2];
    int s2 = srcs[p0 + j + 4], s3 = srcs[p0 + j + 6];
    float l0 = als[s0 * 8 + hB] + aldB;
    float l1 = als[s1 * 8 + hB] + aldB;
    float l2 = als[s2 * 8 + hB] + aldB;
    float l3 = als[s3 * 8 + hB] + aldB;
    uint2v h0 = *(const uint2v*)(h + (long)s0 * 128 + c0);
    uint2v h1 = *(const uint2v*)(h + (long)s1 * 128 + c0);
    uint2v h2 = *(const uint2v*)(h + (long)s2 * 128 + c0);
    uint2v h3 = *(const uint2v*)(h + (long)s3 * 128 + c0);
    l0 = l0 > 0.f ? l0 : 0.2f * l0;
    l1 = l1 > 0.f ? l1 : 0.2f * l1;
    l2 = l2 > 0.f ? l2 : 0.2f * l2;
    l3 = l3 > 0.f ? l3 : 0.2f * l3;
    float e0 = __expf(l0), e1 = __expf(l1), e2 = __expf(l2), e3 = __expf(l3);
    dsum += e0 + e1 + e2 + e3;
    a0 += e0 * f16lo(h0[0]) + e1 * f16lo(h1[0]) + e2 * f16lo(h2[0]) + e3 * f16lo(h3[0]);
    a1 += e0 * f16hi(h0[0]) + e1 * f16hi(h1[0]) + e2 * f16hi(h2[0]) + e3 * f16hi(h3[0]);
    a2 += e0 * f16lo(h0[1]) + e1 * f16lo(h1[1]) + e2 * f16lo(h2[1]) + e3 * f16lo(h3[1]);
    a3 += e0 * f16hi(h0[1]) + e1 * f16hi(h1[1]) + e2 * f16hi(h2[1]) + e3 * f16hi(h3[1]);
  }
  for (; j < deg; j += 2) {
    int s = srcs[p0 + j];
    float l = als[s * 8 + hB] + aldB;
    l = l > 0.f ? l : 0.2f * l;
    float e = __expf(l);
    uint2v hv = *(const uint2v*)(h + (long)s * 128 + c0);
    dsum += e;
    a0 += e * f16lo(hv[0]);
    a1 += e * f16hi(hv[0]);
    a2 += e * f16lo(hv[1]);
    a3 += e * f16hi(hv[1]);
  }
  a0 += __shfl_xor(a0, 32);
  a1 += __shfl_xor(a1, 32);
  a2 += __shfl_xor(a2, 32);
  a3 += __shfl_xor(a3, 32);
  dsum += __shfl_xor(dsum, 32);
  if (half == 0) {
    float inv = 1.f / (dsum + 1e-16f);
    float o0 = a0 * inv + bias[c0];
    float o1 = a1 * inv + bias[c0 + 1];
    float o2 = a2 * inv + bias[c0 + 2];
    float o3 = a3 * inv + bias[c0 + 3];
    o0 = o0 > 0.f ? o0 : (__expf(o0) - 1.f);
    o1 = o1 > 0.f ? o1 : (__expf(o1) - 1.f);
    o2 = o2 > 0.f ? o2 : (__expf(o2) - 1.f);
    o3 = o3 > 0.f ? o3 : (__expf(o3) - 1.f);
    uint2v po;
    po[0] = __builtin_bit_cast(unsigned int, __builtin_amdgcn_cvt_pkrtz(o0, o1));
    po[1] = __builtin_bit_cast(unsigned int, __builtin_amdgcn_cvt_pkrtz(o2, o3));
    *(uint2v*)(out + (long)wid * 128 + c0) = po;
  }
}

// ---------------- per-dst aggregation, H=1, C=16, fp32, no max, 4-batch --------

__global__ void k_agg16(const float* __restrict__ h, const float* __restrict__ als,
                        const float* __restrict__ ald, const int* __restrict__ ptr,
                        const int* __restrict__ srcs, const float* __restrict__ bias,
                        float* __restrict__ out, int n, int lda) {
  int wid = (int)(((long)blockIdx.x * blockDim.x + threadIdx.x) >> 6);
  if (wid >= n) return;
  int lane = threadIdx.x & 63;
  int p0 = ptr[wid], deg = ptr[wid + 1] - p0;
  float aldv = ald[wid];
  int g = lane >> 4, c = lane & 15;
  float acc = 0.f, dsum = 0.f;
  int j = g;
  for (; j + 12 < deg; j += 16) {
    int s0 = srcs[p0 + j],     s1 = srcs[p0 + j + 4];
    int s2 = srcs[p0 + j + 8], s3 = srcs[p0 + j + 12];
    float l0 = als[s0] + aldv, l1 = als[s1] + aldv;
    float l2 = als[s2] + aldv, l3 = als[s3] + aldv;
    float h0 = h[(long)s0 * lda + c], h1 = h[(long)s1 * lda + c];
    float h2 = h[(long)s2 * lda + c], h3 = h[(long)s3 * lda + c];
    l0 = l0 > 0.f ? l0 : 0.2f * l0;
    l1 = l1 > 0.f ? l1 : 0.2f * l1;
    l2 = l2 > 0.f ? l2 : 0.2f * l2;
    l3 = l3 > 0.f ? l3 : 0.2f * l3;
    float e0 = __expf(l0), e1 = __expf(l1), e2 = __expf(l2), e3 = __expf(l3);
    dsum += e0 + e1 + e2 + e3;
    acc += e0 * h0 + e1 * h1 + e2 * h2 + e3 * h3;
  }
  for (; j < deg; j += 4) {
    int s = srcs[p0 + j];
    float l = als[s] + aldv;
    l = l > 0.f ? l : 0.2f * l;
    float e = __expf(l);
    dsum += e;
    acc += e * h[(long)s * lda + c];
  }
  #pragma unroll
  for (int d = 16; d < 64; d <<= 1) {
    acc += __shfl_xor(acc, d);
    dsum += __shfl_xor(dsum, d);
  }
  if (lane < 16)
    out[(long)wid * 16 + lane] = acc / (dsum + 1e-16f) + bias[lane];
}

// ---------------- launch ----------------

extern "C" void kernel_launch(void* const* d_in, const int* in_sizes, int n_in,
                              void* d_out, int out_size, void* d_ws, size_t ws_size,
                              hipStream_t stream) {
  const float* x  = (const float*)d_in[0];
  const int*   ei = (const int*)d_in[1];
  const float* W0 = (const float*)d_in[2];
  const float* as0= (const float*)d_in[3];
  const float* ad0= (const float*)d_in[4];
  const float* b0 = (const float*)d_in[5];
  const float* W1 = (const float*)d_in[6];
  const float* as1= (const float*)d_in[7];
  const float* ad1= (const float*)d_in[8];
  const float* b1 = (const float*)d_in[9];
  const float* W2 = (const float*)d_in[10];
  const float* as2= (const float*)d_in[11];
  const float* ad2= (const float*)d_in[12];
  const float* b2 = (const float*)d_in[13];
  float* out = (float*)d_out;

  int E = in_sizes[1] / 2;
  int n = in_sizes[0] / GENES;

  char* ws = (char*)d_ws;
  size_t off = 0;
  auto alloc = [&](size_t bytes) {
    void* p = ws + off;
    off = (off + bytes + 255) & ~(size_t)255;
    return p;
  };
  int* ptr   = (int*)alloc((size_t)(n + 1) * sizeof(int));
  int* cur   = (int*)alloc((size_t)n * sizeof(int));
  int* bsum  = (int*)alloc(512 * sizeof(int));
  int* srcs  = (int*)alloc((size_t)E * sizeof(int));
  unsigned short* Ah = (unsigned short*)alloc((size_t)n * 128 * sizeof(unsigned short));
  unsigned short* Bh = (unsigned short*)alloc((size_t)n * 128 * sizeof(unsigned short));
  float* A2  = (float*)alloc((size_t)n * 16 * sizeof(float));
  float* als = (float*)alloc((size_t)n * 8 * sizeof(float));
  float* ald = (float*)alloc((size_t)n * 8 * sizeof(float));
  unsigned short* P = (unsigned short*)alloc((size_t)163840 * sizeof(unsigned short));
  unsigned short* P0 = P;
  unsigned short* P1 = P + 131072;
  unsigned short* P2 = P + 147456;

  int eb = (E + 255) / 256;
  int nb = (n + 255) / 256;
  hipMemsetAsync(cur, 0, (size_t)n * sizeof(int), stream);
  k_deg<<<eb, 256, 0, stream>>>(ei, cur, E);
  k_scan1<<<nb, 256, 0, stream>>>(cur, ptr, bsum, n);   // zeroes cur in place
  k_scan2<<<1, 256, 0, stream>>>(bsum, nb);
  k_scan3<<<nb, 256, 0, stream>>>(ptr, bsum, n);
  k_scatter<<<eb, 256, 0, stream>>>(ei, ptr, cur, srcs, E);
  k_wpackall<<<640, 256, 0, stream>>>(W0, W1, W2, P, GENES);

  int mgb  = (n + 63) / 64;
  int aggb = (int)(((long)n * 64 + 255) / 256);

  // layer 0: x @ W0 -> Ah fp16 (+als/ald), aggregate -> Bh fp16 (ELU)
  k_mgemm9<8, false, true><<<mgb, 512, 0, stream>>>(
      x, P0, Ah, als, ald, as0, ad0, n, GENES, 8, 128);
  k_agg128h<<<aggb, 256, 0, stream>>>(Ah, als, ald, ptr, srcs, b0, Bh, n);

  // layer 1: Bh @ W1 -> Ah fp16 (+als/ald), aggregate -> Bh fp16 (ELU)
  k_mgemm9<8, true, true><<<mgb, 512, 0, stream>>>(
      Bh, P1, Ah, als, ald, as1, ad1, n, 128, 1, 128);
  k_agg128h<<<aggb, 256, 0, stream>>>(Ah, als, ald, ptr, srcs, b1, Bh, n);

  // layer 2: Bh @ W2 (padded) -> A2 fp32 [n][16] (+als/ald H=1), aggregate -> out
  k_mgemm9<1, true, false><<<mgb, 512, 0, stream>>>(
      Bh, P2, A2, als, ald, as2, ad2, n, 128, 1, 16);
  k_agg16<<<aggb, 256, 0, stream>>>(A2, als, ald, ptr, srcs, b2, out, n, 16);
}